// Round 4
// baseline (108.734 us; speedup 1.0000x reference)
//
#include <hip/hip_runtime.h>

// Unsharp-mask: out = img + param * (img - gaussblur25(img)), param = 5*(tanh(f[b,0])*.5+.5)
// img: (16,3,512,512) fp32. Output: [out (12582912 fp32)] ++ [param (16 fp32)].
//
// Two streaming kernels, no LDS (working set is L3-resident):
//   k1: horizontal 25-tap blur img -> ws (8 outputs/thread from 8 float4 loads;
//       edge groups xg in {0,1,61,62,63} use scalar reflected loads)
//   k2: vertical 25-tap via 25-deep sliding register window + fused epilogue

#define RADIUS 12
#define KS     25
#define IMG_W  512
#define IMG_H  512
#define PLANE  (IMG_W * IMG_H)
#define NPLANE 48

__device__ __forceinline__ int reflect512(int i) {
    i = (i < 0) ? -i : i;
    return (i >= 512) ? (1022 - i) : i;
}

__device__ __forceinline__ void gauss_w(float* w) {
    float s = 0.f;
#pragma unroll
    for (int i = 0; i < KS; ++i) {
        float x = (float)(i - RADIUS) * 0.2f;
        w[i] = __expf(-0.5f * x * x);
        s += w[i];
    }
    const float inv = 1.0f / s;
#pragma unroll
    for (int i = 0; i < KS; ++i) w[i] *= inv;
}

// ---- k1: horizontal blur. block 256 = 64 x-groups x 4 rows; thread: 8 consecutive x ----
// Fast path requires taps x0-12 .. x0+19 all in [0,511]: x0 in [12,480] -> xg in [2,60].
__global__ __launch_bounds__(256) void hblur_kernel(
    const float* __restrict__ img, float* __restrict__ ws)
{
    float w[KS]; gauss_w(w);
    const int xg = threadIdx.x & 63;
    const int y  = blockIdx.x * 4 + (threadIdx.x >> 6);
    const int pl = blockIdx.y;
    const float* __restrict__ rowp = img + (size_t)pl * PLANE + (size_t)y * IMG_W;
    const int x0 = xg * 8;

    float r[32];
    if (xg >= 2 && xg <= 60) {
#pragma unroll
        for (int i = 0; i < 8; ++i)
            *(float4*)&r[4 * i] = *(const float4*)(rowp + x0 - 12 + 4 * i);
    } else {
#pragma unroll
        for (int j = 0; j < 32; ++j)
            r[j] = rowp[reflect512(x0 - 12 + j)];
    }

    float acc[8];
#pragma unroll
    for (int o = 0; o < 8; ++o) {
        float a = 0.f;
#pragma unroll
        for (int k = 0; k < KS; ++k) a += w[k] * r[o + k];
        acc[o] = a;
    }
    float* outp = ws + (size_t)pl * PLANE + (size_t)y * IMG_W + x0;
    *(float4*)outp       = make_float4(acc[0], acc[1], acc[2], acc[3]);
    *(float4*)(outp + 4) = make_float4(acc[4], acc[5], acc[6], acc[7]);
}

// ---- k2: vertical blur + epilogue. block 256 = 128 float4-cols x 2 y-subgroups;
//      thread: one float4 column x 16 rows, 25-deep sliding register window ----
__global__ __launch_bounds__(256) void vusm_kernel(
    const float* __restrict__ ws, const float* __restrict__ img,
    const float* __restrict__ feat,
    float* __restrict__ out, float* __restrict__ out_param)
{
    float w[KS]; gauss_w(w);
    const int x4 = (threadIdx.x & 127) * 4;
    const int y0 = (blockIdx.x * 2 + (threadIdx.x >> 7)) * 16;
    const int pl = blockIdx.y;
    const int b  = pl / 3;
    const float param = (tanhf(feat[b * 8]) * 0.5f + 0.5f) * 5.0f;

    const float* __restrict__ wp = ws  + (size_t)pl * PLANE + x4;
    const float* __restrict__ ip = img + (size_t)pl * PLANE + x4;
    float* __restrict__       op = out + (size_t)pl * PLANE + x4;

    float4 win[KS];
#pragma unroll
    for (int j = 0; j < 24; ++j)
        win[j] = *(const float4*)(wp + (size_t)reflect512(y0 + j - 12) * IMG_W);

#pragma unroll
    for (int s = 0; s < 16; ++s) {
        win[(24 + s) % 25] = *(const float4*)(wp + (size_t)reflect512(y0 + 12 + s) * IMG_W);
        float4 a = make_float4(0.f, 0.f, 0.f, 0.f);
#pragma unroll
        for (int k = 0; k < KS; ++k) {
            const float4 t = win[(s + k) % 25];
            const float wk = w[k];
            a.x += wk * t.x; a.y += wk * t.y; a.z += wk * t.z; a.w += wk * t.w;
        }
        const float4 v = *(const float4*)(ip + (size_t)(y0 + s) * IMG_W);
        float4 o;
        o.x = v.x + param * (v.x - a.x);
        o.y = v.y + param * (v.y - a.y);
        o.z = v.z + param * (v.z - a.z);
        o.w = v.w + param * (v.w - a.w);
        *(float4*)(op + (size_t)(y0 + s) * IMG_W) = o;
    }

    if (threadIdx.x == 0 && blockIdx.x == 0 && pl == b * 3)
        out_param[b] = param;
}

// ---- fallback: fused LDS kernel (used only if ws is too small) ----
#define TILE 64
#define PT   (TILE + 2 * RADIUS)
__global__ __launch_bounds__(256) void usm_fused_kernel(
    const float* __restrict__ img, const float* __restrict__ feat,
    float* __restrict__ out, float* __restrict__ out_param)
{
    __shared__ float tileA[PT][PT];
    __shared__ float tmpB[PT][TILE];
    const int tid = threadIdx.x;
    const int tx0 = blockIdx.x * TILE, ty0 = blockIdx.y * TILE;
    const int zc = blockIdx.z, b = zc / 3;
    float w[KS]; gauss_w(w);
    const float param = (tanhf(feat[b * 8]) * 0.5f + 0.5f) * 5.0f;
    const float* __restrict__ src = img + (size_t)zc * PLANE;
    const bool xedge = (blockIdx.x == 0) || (blockIdx.x == 7);
    for (int li = tid; li < PT * (PT / 4); li += 256) {
        int py = li / 22, x4 = li - py * 22;
        int gy = reflect512(ty0 - RADIUS + py);
        const float* rowp = src + gy * IMG_W;
        int gx = tx0 - RADIUS + x4 * 4;
        float4 v;
        if (!xedge) v = *(const float4*)(rowp + gx);
        else { v.x = rowp[reflect512(gx)]; v.y = rowp[reflect512(gx + 1)];
               v.z = rowp[reflect512(gx + 2)]; v.w = rowp[reflect512(gx + 3)]; }
        *(float4*)&tileA[py][x4 * 4] = v;
    }
    __syncthreads();
    for (int li = tid; li < PT * (TILE / 8); li += 256) {
        int py = li >> 3, g = li & 7;
        float r[32];
#pragma unroll
        for (int i = 0; i < 8; ++i) *(float4*)&r[4 * i] = *(const float4*)&tileA[py][g * 8 + 4 * i];
        float acc[8];
#pragma unroll
        for (int o = 0; o < 8; ++o) {
            float a = 0.f;
#pragma unroll
            for (int k = 0; k < KS; ++k) a += w[k] * r[o + k];
            acc[o] = a;
        }
        *(float4*)&tmpB[py][g * 8]     = make_float4(acc[0], acc[1], acc[2], acc[3]);
        *(float4*)&tmpB[py][g * 8 + 4] = make_float4(acc[4], acc[5], acc[6], acc[7]);
    }
    __syncthreads();
    const int tx4 = (tid & 15) * 4, ry0 = (tid >> 4) * 4;
    float ax[4], ay[4], az[4], aw[4];
#pragma unroll
    for (int d = 0; d < 4; ++d) ax[d] = ay[d] = az[d] = aw[d] = 0.f;
#pragma unroll
    for (int k = 0; k < KS + 3; ++k) {
        float4 t = *(const float4*)&tmpB[ry0 + k][tx4];
#pragma unroll
        for (int d = 0; d < 4; ++d) {
            int kk = k - d;
            if (kk >= 0 && kk < KS) {
                float wk = w[kk];
                ax[d] += wk * t.x; ay[d] += wk * t.y; az[d] += wk * t.z; aw[d] += wk * t.w;
            }
        }
    }
    float* __restrict__ dst = out + (size_t)zc * PLANE;
#pragma unroll
    for (int d = 0; d < 4; ++d) {
        int oy = ry0 + d;
        float4 v = *(const float4*)&tileA[oy + RADIUS][tx4 + RADIUS];
        float4 o;
        o.x = v.x + param * (v.x - ax[d]); o.y = v.y + param * (v.y - ay[d]);
        o.z = v.z + param * (v.z - az[d]); o.w = v.w + param * (v.w - aw[d]);
        *(float4*)&dst[(size_t)(ty0 + oy) * IMG_W + tx0 + tx4] = o;
    }
    if (tid == 0 && blockIdx.x == 0 && blockIdx.y == 0 && (zc - b * 3) == 0)
        out_param[b] = param;
}

extern "C" void kernel_launch(void* const* d_in, const int* in_sizes, int n_in,
                              void* d_out, int out_size, void* d_ws, size_t ws_size,
                              hipStream_t stream) {
    const float* img  = (const float*)d_in[0];
    const float* feat = (const float*)d_in[1];
    float* out       = (float*)d_out;
    float* out_param = (float*)d_out + (size_t)NPLANE * PLANE;

    const size_t need = (size_t)NPLANE * PLANE * sizeof(float);   // 50.33 MB
    if (ws_size >= need) {
        float* ws = (float*)d_ws;
        hblur_kernel<<<dim3(IMG_H / 4, NPLANE), 256, 0, stream>>>(img, ws);
        vusm_kernel<<<dim3(IMG_H / 32, NPLANE), 256, 0, stream>>>(ws, img, feat, out, out_param);
    } else {
        usm_fused_kernel<<<dim3(8, 8, NPLANE), 256, 0, stream>>>(img, feat, out, out_param);
    }
}

// Round 5
// 107.539 us; speedup vs baseline: 1.0111x; 1.0111x over previous
//
#include <hip/hip_runtime.h>

// Unsharp-mask: out = img + param * (img - gaussblur25(img)), param = 5*(tanh(f[b,0])*.5+.5)
// img: (16,3,512,512) fp32. Output: [out (12582912 fp32)] ++ [param (16 fp32)].
//
// Two streaming kernels, no LDS:
//   k1: horizontal 25-tap blur img -> ws. 8 outputs/thread from float4 q[8]
//       (NO scalar-array punning -> stays in VGPRs). Weights in SGPRs.
//   k2: vertical 25-tap via 25-deep float4 sliding window + fused epilogue.

#define RADIUS 12
#define KS     25
#define IMG_W  512
#define IMG_H  512
#define PLANE  (IMG_W * IMG_H)
#define NPLANE 48

__device__ __forceinline__ int reflect512(int i) {
    i = (i < 0) ? -i : i;
    return (i >= 512) ? (1022 - i) : i;
}

__device__ __forceinline__ float get_elem(const float4& v, int c) {
    return (c == 0) ? v.x : (c == 1) ? v.y : (c == 2) ? v.z : v.w;
}
__device__ __forceinline__ void set_elem(float4& v, int c, float x) {
    if (c == 0) v.x = x; else if (c == 1) v.y = x; else if (c == 2) v.z = x; else v.w = x;
}

__device__ __forceinline__ void gauss_w(float* w) {
    float s = 0.f;
#pragma unroll
    for (int i = 0; i < KS; ++i) {
        float x = (float)(i - RADIUS) * 0.2f;
        w[i] = __expf(-0.5f * x * x);
        s += w[i];
    }
    const float inv = 1.0f / s;
#pragma unroll
    for (int i = 0; i < KS; ++i) w[i] *= inv;
    // wave-uniform -> hoist to SGPRs, freeing 25 VGPRs
#pragma unroll
    for (int i = 0; i < KS; ++i)
        w[i] = __int_as_float(__builtin_amdgcn_readfirstlane(__float_as_int(w[i])));
}

// ---- k1: horizontal blur. block 256 = 64 x-groups x 4 rows; thread: 8 consecutive x ----
// Fast path needs taps x0-12 .. x0+19 within [0,511]: xg in [2,61].
__global__ __launch_bounds__(256, 2) void hblur_kernel(
    const float* __restrict__ img, float* __restrict__ ws)
{
    float w[KS]; gauss_w(w);
    const int xg = threadIdx.x & 63;
    const int y  = blockIdx.x * 4 + (threadIdx.x >> 6);
    const int pl = blockIdx.y;
    const float* __restrict__ rowp = img + (size_t)pl * PLANE + (size_t)y * IMG_W;
    const int x0 = xg * 8;

    float4 q[8];   // taps x0-12 .. x0+19
    if (xg >= 2 && xg <= 61) {
#pragma unroll
        for (int i = 0; i < 8; ++i)
            q[i] = *(const float4*)(rowp + x0 - 12 + 4 * i);
    } else {
#pragma unroll
        for (int j = 0; j < 32; ++j)
            set_elem(q[j >> 2], j & 3, rowp[reflect512(x0 - 12 + j)]);
    }

    float acc[8];
#pragma unroll
    for (int o = 0; o < 8; ++o) {
        float a = 0.f;
#pragma unroll
        for (int k = 0; k < KS; ++k) {
            const int idx = o + k;
            a += w[k] * get_elem(q[idx >> 2], idx & 3);
        }
        acc[o] = a;
    }
    float* outp = ws + (size_t)pl * PLANE + (size_t)y * IMG_W + x0;
    *(float4*)outp       = make_float4(acc[0], acc[1], acc[2], acc[3]);
    *(float4*)(outp + 4) = make_float4(acc[4], acc[5], acc[6], acc[7]);
}

// ---- k2: vertical blur + epilogue. thread: one float4 column x 16 rows,
//      25-deep sliding register window (all indices static after unroll) ----
__global__ __launch_bounds__(256) void vusm_kernel(
    const float* __restrict__ ws, const float* __restrict__ img,
    const float* __restrict__ feat,
    float* __restrict__ out, float* __restrict__ out_param)
{
    float w[KS]; gauss_w(w);
    const int x4 = (threadIdx.x & 127) * 4;
    const int y0 = (blockIdx.x * 2 + (threadIdx.x >> 7)) * 16;
    const int pl = blockIdx.y;
    const int b  = pl / 3;
    const float param = (tanhf(feat[b * 8]) * 0.5f + 0.5f) * 5.0f;

    const float* __restrict__ wp = ws  + (size_t)pl * PLANE + x4;
    const float* __restrict__ ip = img + (size_t)pl * PLANE + x4;
    float* __restrict__       op = out + (size_t)pl * PLANE + x4;

    float4 win[KS];
#pragma unroll
    for (int j = 0; j < 24; ++j)
        win[j] = *(const float4*)(wp + (size_t)reflect512(y0 + j - 12) * IMG_W);

#pragma unroll
    for (int s = 0; s < 16; ++s) {
        win[(24 + s) % 25] = *(const float4*)(wp + (size_t)reflect512(y0 + 12 + s) * IMG_W);
        float4 a = make_float4(0.f, 0.f, 0.f, 0.f);
#pragma unroll
        for (int k = 0; k < KS; ++k) {
            const float4 t = win[(s + k) % 25];
            const float wk = w[k];
            a.x += wk * t.x; a.y += wk * t.y; a.z += wk * t.z; a.w += wk * t.w;
        }
        const float4 v = *(const float4*)(ip + (size_t)(y0 + s) * IMG_W);
        float4 o;
        o.x = v.x + param * (v.x - a.x);
        o.y = v.y + param * (v.y - a.y);
        o.z = v.z + param * (v.z - a.z);
        o.w = v.w + param * (v.w - a.w);
        *(float4*)(op + (size_t)(y0 + s) * IMG_W) = o;
    }

    if (threadIdx.x == 0 && blockIdx.x == 0 && pl == b * 3)
        out_param[b] = param;
}

// ---- fallback: fused LDS kernel (used only if ws is too small) ----
#define TILE 64
#define PT   (TILE + 2 * RADIUS)
__global__ __launch_bounds__(256) void usm_fused_kernel(
    const float* __restrict__ img, const float* __restrict__ feat,
    float* __restrict__ out, float* __restrict__ out_param)
{
    __shared__ float tileA[PT][PT];
    __shared__ float tmpB[PT][TILE];
    const int tid = threadIdx.x;
    const int tx0 = blockIdx.x * TILE, ty0 = blockIdx.y * TILE;
    const int zc = blockIdx.z, b = zc / 3;
    float w[KS]; gauss_w(w);
    const float param = (tanhf(feat[b * 8]) * 0.5f + 0.5f) * 5.0f;
    const float* __restrict__ src = img + (size_t)zc * PLANE;
    const bool xedge = (blockIdx.x == 0) || (blockIdx.x == 7);
    for (int li = tid; li < PT * (PT / 4); li += 256) {
        int py = li / 22, x4 = li - py * 22;
        int gy = reflect512(ty0 - RADIUS + py);
        const float* rowp = src + gy * IMG_W;
        int gx = tx0 - RADIUS + x4 * 4;
        float4 v;
        if (!xedge) v = *(const float4*)(rowp + gx);
        else { v.x = rowp[reflect512(gx)]; v.y = rowp[reflect512(gx + 1)];
               v.z = rowp[reflect512(gx + 2)]; v.w = rowp[reflect512(gx + 3)]; }
        *(float4*)&tileA[py][x4 * 4] = v;
    }
    __syncthreads();
    for (int li = tid; li < PT * (TILE / 8); li += 256) {
        int py = li >> 3, g = li & 7;
        float4 q[8];
#pragma unroll
        for (int i = 0; i < 8; ++i) q[i] = *(const float4*)&tileA[py][g * 8 + 4 * i];
        float acc[8];
#pragma unroll
        for (int o = 0; o < 8; ++o) {
            float a = 0.f;
#pragma unroll
            for (int k = 0; k < KS; ++k) {
                const int idx = o + k;
                a += w[k] * get_elem(q[idx >> 2], idx & 3);
            }
            acc[o] = a;
        }
        *(float4*)&tmpB[py][g * 8]     = make_float4(acc[0], acc[1], acc[2], acc[3]);
        *(float4*)&tmpB[py][g * 8 + 4] = make_float4(acc[4], acc[5], acc[6], acc[7]);
    }
    __syncthreads();
    const int tx4 = (tid & 15) * 4, ry0 = (tid >> 4) * 4;
    float ax[4], ay[4], az[4], aw[4];
#pragma unroll
    for (int d = 0; d < 4; ++d) ax[d] = ay[d] = az[d] = aw[d] = 0.f;
#pragma unroll
    for (int k = 0; k < KS + 3; ++k) {
        float4 t = *(const float4*)&tmpB[ry0 + k][tx4];
#pragma unroll
        for (int d = 0; d < 4; ++d) {
            int kk = k - d;
            if (kk >= 0 && kk < KS) {
                float wk = w[kk];
                ax[d] += wk * t.x; ay[d] += wk * t.y; az[d] += wk * t.z; aw[d] += wk * t.w;
            }
        }
    }
    float* __restrict__ dst = out + (size_t)zc * PLANE;
#pragma unroll
    for (int d = 0; d < 4; ++d) {
        int oy = ry0 + d;
        float4 v = *(const float4*)&tileA[oy + RADIUS][tx4 + RADIUS];
        float4 o;
        o.x = v.x + param * (v.x - ax[d]); o.y = v.y + param * (v.y - ay[d]);
        o.z = v.z + param * (v.z - az[d]); o.w = v.w + param * (v.w - aw[d]);
        *(float4*)&dst[(size_t)(ty0 + oy) * IMG_W + tx0 + tx4] = o;
    }
    if (tid == 0 && blockIdx.x == 0 && blockIdx.y == 0 && (zc - b * 3) == 0)
        out_param[b] = param;
}

extern "C" void kernel_launch(void* const* d_in, const int* in_sizes, int n_in,
                              void* d_out, int out_size, void* d_ws, size_t ws_size,
                              hipStream_t stream) {
    const float* img  = (const float*)d_in[0];
    const float* feat = (const float*)d_in[1];
    float* out       = (float*)d_out;
    float* out_param = (float*)d_out + (size_t)NPLANE * PLANE;

    const size_t need = (size_t)NPLANE * PLANE * sizeof(float);   // 50.33 MB
    if (ws_size >= need) {
        float* ws = (float*)d_ws;
        hblur_kernel<<<dim3(IMG_H / 4, NPLANE), 256, 0, stream>>>(img, ws);
        vusm_kernel<<<dim3(IMG_H / 32, NPLANE), 256, 0, stream>>>(ws, img, feat, out, out_param);
    } else {
        usm_fused_kernel<<<dim3(8, 8, NPLANE), 256, 0, stream>>>(img, feat, out, out_param);
    }
}